// Round 1
// baseline (36.429 us; speedup 1.0000x reference)
//
#include <hip/hip_runtime.h>

// Problem constants (from reference)
#define NRB 512
#define NTK 1024
#define DD  64
#define GHH 128

// Workspace layout (floats):
//   HR  [512][128]  @ 0
//   HTB [1024][128] @ 65536
//   a   [512]       @ 196608
//   c   [1024]      @ 197120
//   wb  [128]       @ 198144   (0.45 * Wm2)
// total 198272 floats = 793 KB

// ---------------------------------------------------------------------------
// Kernel A: prep. Robot blocks (0..127): 4 robots each, 3-layer MLP ->
// HR[n][h] and a[n]. Task blocks (128..383): 4 tasks each ->
// HTB[m][h] = x_task@Wm1[:,128:].T + bm1 and c[m].
// ---------------------------------------------------------------------------
__global__ __launch_bounds__(128) void prep_kernel(
    const float* __restrict__ xr, const float* __restrict__ xt,
    const float* __restrict__ Wv1, const float* __restrict__ bv1,
    const float* __restrict__ Wv2, const float* __restrict__ bv2,
    const float* __restrict__ Wm1, const float* __restrict__ bm1,
    const float* __restrict__ Wm2, const float* __restrict__ bm2,
    float* __restrict__ HR, float* __restrict__ HTB,
    float* __restrict__ av, float* __restrict__ cv, float* __restrict__ wbv)
{
    const int i = threadIdx.x;      // 0..127
    __shared__ float xs[4][DD];     // 4 input rows
    __shared__ float sA[4][GHH];    // h1
    __shared__ float sB[4][GHH];    // h
    __shared__ float sR[4][GHH];    // reduction scratch

    if (blockIdx.x < NRB / 4) {
        // -------- robot path --------
        const int r0 = blockIdx.x * 4;
        ((float*)xs)[i]       = xr[r0 * DD + i];
        ((float*)xs)[128 + i] = xr[r0 * DD + 128 + i];
        __syncthreads();

        // phase 1: h1[r][i] = lrelu(bv1[i] + x[r] . Wv1[i, 128:192])
        {
            float4 w[16];
            const float4* wp = reinterpret_cast<const float4*>(Wv1 + i * 192 + 128);
            #pragma unroll
            for (int q = 0; q < 16; ++q) w[q] = wp[q];
            const float b = bv1[i];
            for (int r = 0; r < 4; ++r) {
                float acc = b;
                #pragma unroll
                for (int q = 0; q < 16; ++q) {
                    acc = fmaf(w[q].x, xs[r][q*4+0], acc);
                    acc = fmaf(w[q].y, xs[r][q*4+1], acc);
                    acc = fmaf(w[q].z, xs[r][q*4+2], acc);
                    acc = fmaf(w[q].w, xs[r][q*4+3], acc);
                }
                sA[r][i] = (acc >= 0.f) ? acc : 0.1f * acc;
            }
        }
        __syncthreads();

        // phase 2: h[r][i] = bv2[i] + h1[r] . Wv2[i, :]
        {
            float4 w[32];
            const float4* wp = reinterpret_cast<const float4*>(Wv2 + i * GHH);
            #pragma unroll
            for (int q = 0; q < 32; ++q) w[q] = wp[q];
            const float b = bv2[i];
            for (int r = 0; r < 4; ++r) {
                float acc = b;
                const float4* hp = reinterpret_cast<const float4*>(sA[r]);
                #pragma unroll
                for (int q = 0; q < 32; ++q) {
                    float4 h4 = hp[q];
                    acc = fmaf(w[q].x, h4.x, acc);
                    acc = fmaf(w[q].y, h4.y, acc);
                    acc = fmaf(w[q].z, h4.z, acc);
                    acc = fmaf(w[q].w, h4.w, acc);
                }
                sB[r][i] = acc;   // no activation on h
            }
        }
        __syncthreads();

        // phase 3: hr[r][i] = h[r] . Wm1[i, :128];  a[n] = 0.55 * sum w*hr
        {
            float4 w[32];
            const float4* wp = reinterpret_cast<const float4*>(Wm1 + i * 192);
            #pragma unroll
            for (int q = 0; q < 32; ++q) w[q] = wp[q];
            const float wm2 = Wm2[i];
            for (int r = 0; r < 4; ++r) {
                float acc = 0.f;
                const float4* hp = reinterpret_cast<const float4*>(sB[r]);
                #pragma unroll
                for (int q = 0; q < 32; ++q) {
                    float4 h4 = hp[q];
                    acc = fmaf(w[q].x, h4.x, acc);
                    acc = fmaf(w[q].y, h4.y, acc);
                    acc = fmaf(w[q].z, h4.z, acc);
                    acc = fmaf(w[q].w, h4.w, acc);
                }
                HR[(r0 + r) * GHH + i] = acc;
                sR[r][i] = wm2 * acc;
            }
        }
        __syncthreads();
        if (i < 4) {
            float s = 0.f;
            for (int k = 0; k < GHH; ++k) s += sR[i][k];
            av[r0 + i] = 0.55f * s;
        }
    } else {
        // -------- task path --------
        const int t0 = (blockIdx.x - NRB / 4) * 4;
        ((float*)xs)[i]       = xt[t0 * DD + i];
        ((float*)xs)[128 + i] = xt[t0 * DD + 128 + i];
        __syncthreads();

        float4 w[16];
        const float4* wp = reinterpret_cast<const float4*>(Wm1 + i * 192 + 128);
        #pragma unroll
        for (int q = 0; q < 16; ++q) w[q] = wp[q];
        const float b   = bm1[i];
        const float wm2 = Wm2[i];
        for (int t = 0; t < 4; ++t) {
            float acc = b;
            #pragma unroll
            for (int q = 0; q < 16; ++q) {
                acc = fmaf(w[q].x, xs[t][q*4+0], acc);
                acc = fmaf(w[q].y, xs[t][q*4+1], acc);
                acc = fmaf(w[q].z, xs[t][q*4+2], acc);
                acc = fmaf(w[q].w, xs[t][q*4+3], acc);
            }
            HTB[(t0 + t) * GHH + i] = acc;   // includes bm1
            sR[t][i] = wm2 * acc;
        }
        __syncthreads();
        if (i < 4) {
            float s = 0.f;
            for (int k = 0; k < GHH; ++k) s += sR[i][k];
            cv[t0 + i] = 0.55f * s + bm2[0];
        }
        if (blockIdx.x == NRB / 4) wbv[i] = 0.45f * wm2;
    }
}

// ---------------------------------------------------------------------------
// Kernel B: scores[n][m] = sum_h wb[h]*|HR[n,h]+HTB[m,h]| + a[n] + c[m]
// Grid: 256 blocks = 4 m-chunks x 64 n-groups, 256 threads.
// Thread owns one m (htb row register-resident in 32-float chunks),
// 8 n's with hr/wb via wave-uniform (scalar) loads. 2 VALU / element.
// ---------------------------------------------------------------------------
__global__ __launch_bounds__(256) void score_kernel(
    const float* __restrict__ HR, const float* __restrict__ HTB,
    const float* __restrict__ av, const float* __restrict__ cv,
    const float* __restrict__ wbv, float* __restrict__ out)
{
    const int mc = blockIdx.x & 3;
    const int ng = blockIdx.x >> 2;
    const int m  = mc * 256 + threadIdx.x;
    const int n0 = ng * 8;

    float accA[8], accB[8];
    #pragma unroll
    for (int k = 0; k < 8; ++k) { accA[k] = 0.f; accB[k] = 0.f; }

    const float4* htbp = reinterpret_cast<const float4*>(HTB + m * GHH);

    for (int hc = 0; hc < 4; ++hc) {
        float4 hb[8];
        #pragma unroll
        for (int q = 0; q < 8; ++q) hb[q] = htbp[hc * 8 + q];
        float4 wr[8];
        const float4* wp = reinterpret_cast<const float4*>(wbv + hc * 32);
        #pragma unroll
        for (int q = 0; q < 8; ++q) wr[q] = wp[q];

        #pragma unroll
        for (int nn = 0; nn < 8; ++nn) {
            const float4* hrp =
                reinterpret_cast<const float4*>(HR + (n0 + nn) * GHH + hc * 32);
            float a0 = 0.f, a1 = 0.f;
            #pragma unroll
            for (int q = 0; q < 8; ++q) {
                float4 h4 = hrp[q];
                float x0 = h4.x + hb[q].x;
                float x1 = h4.y + hb[q].y;
                float x2 = h4.z + hb[q].z;
                float x3 = h4.w + hb[q].w;
                a0 = fmaf(wr[q].x, fabsf(x0), a0);
                a1 = fmaf(wr[q].y, fabsf(x1), a1);
                a0 = fmaf(wr[q].z, fabsf(x2), a0);
                a1 = fmaf(wr[q].w, fabsf(x3), a1);
            }
            accA[nn] += a0; accB[nn] += a1;
        }
    }

    const float cm = cv[m];
    #pragma unroll
    for (int nn = 0; nn < 8; ++nn)
        out[(n0 + nn) * NTK + m] = accA[nn] + accB[nn] + av[n0 + nn] + cm;
}

// ---------------------------------------------------------------------------
// Kernel C: in-place row softmax over d_out rows of 1024. One block per row.
// ---------------------------------------------------------------------------
__global__ __launch_bounds__(256) void softmax_kernel(float* __restrict__ out)
{
    const int n = blockIdx.x;
    const int t = threadIdx.x;
    float* row = out + n * NTK;

    float v0 = row[t], v1 = row[t + 256], v2 = row[t + 512], v3 = row[t + 768];
    float mx = fmaxf(fmaxf(v0, v1), fmaxf(v2, v3));
    #pragma unroll
    for (int off = 32; off >= 1; off >>= 1)
        mx = fmaxf(mx, __shfl_xor(mx, off, 64));

    __shared__ float sm[4], ss[4];
    const int wid = t >> 6, lane = t & 63;
    if (lane == 0) sm[wid] = mx;
    __syncthreads();
    mx = fmaxf(fmaxf(sm[0], sm[1]), fmaxf(sm[2], sm[3]));

    float e0 = expf(v0 - mx), e1 = expf(v1 - mx);
    float e2 = expf(v2 - mx), e3 = expf(v3 - mx);
    float s = e0 + e1 + e2 + e3;
    #pragma unroll
    for (int off = 32; off >= 1; off >>= 1) s += __shfl_xor(s, off, 64);
    if (lane == 0) ss[wid] = s;
    __syncthreads();
    s = ss[0] + ss[1] + ss[2] + ss[3];

    const float inv = 1.0f / s;
    row[t]       = e0 * inv;
    row[t + 256] = e1 * inv;
    row[t + 512] = e2 * inv;
    row[t + 768] = e3 * inv;
}

extern "C" void kernel_launch(void* const* d_in, const int* in_sizes, int n_in,
                              void* d_out, int out_size, void* d_ws, size_t ws_size,
                              hipStream_t stream)
{
    const float* xr  = (const float*)d_in[0];
    const float* xt  = (const float*)d_in[1];
    // d_in[2]=edge_index, [3]=edge_attr, [4..7]=We1,be1,We2,be2 : provably dead
    const float* Wv1 = (const float*)d_in[8];
    const float* bv1 = (const float*)d_in[9];
    const float* Wv2 = (const float*)d_in[10];
    const float* bv2 = (const float*)d_in[11];
    const float* Wm1 = (const float*)d_in[12];
    const float* bm1 = (const float*)d_in[13];
    const float* Wm2 = (const float*)d_in[14];
    const float* bm2 = (const float*)d_in[15];

    float* ws  = (float*)d_ws;
    float* HR  = ws;
    float* HTB = ws + 65536;
    float* av  = ws + 196608;
    float* cv  = ws + 197120;
    float* wbv = ws + 198144;
    float* out = (float*)d_out;

    hipLaunchKernelGGL(prep_kernel, dim3(384), dim3(128), 0, stream,
                       xr, xt, Wv1, bv1, Wv2, bv2, Wm1, bm1, Wm2, bm2,
                       HR, HTB, av, cv, wbv);
    hipLaunchKernelGGL(score_kernel, dim3(256), dim3(256), 0, stream,
                       HR, HTB, av, cv, wbv, out);
    hipLaunchKernelGGL(softmax_kernel, dim3(512), dim3(256), 0, stream, out);
}